// Round 3
// 738.722 us; speedup vs baseline: 1.2282x; 1.2282x over previous
//
#include <hip/hip_runtime.h>

typedef float f32x4 __attribute__((ext_vector_type(4)));
typedef short s16x8 __attribute__((ext_vector_type(8)));

namespace {
constexpr int NCB = 8;
constexpr int K   = 1024;
constexpr int CD  = 64;
constexpr int T   = 2048;
constexpr int B   = 8;
constexpr int D   = NCB * CD;            // 512
constexpr int TM  = 32;                  // tokens per block
constexpr int NTH = 256;
constexpr int LDK = CD + 4;              // padded LDS row stride (68 floats)

constexpr long ZQ_OFF  = 0;
constexpr long IDX_OFF = (long)B * T * D;               // 8,388,608
constexpr long LG_OFF  = IDX_OFF + (long)B * NCB * T;   // 8,519,680

// workspace layout: [frag bf16 hi/lo, MFMA-B order][cn2 f32]
// frag short8 index = s*16384 + cfg*256 + ks*128 + hl*64 + lane   (cfg = GLOBAL frag idx 0..63)
constexpr size_t FRAG_SH8   = (size_t)NCB * 64 * 2 * 2 * 64;   // 131072
constexpr size_t FRAG_BYTES = FRAG_SH8 * 16;                   // 2 MiB
constexpr size_t CN2_OFF    = FRAG_BYTES;
constexpr size_t WS_NEEDED  = FRAG_BYTES + (size_t)NCB * K * sizeof(float);
}

__device__ __forceinline__ unsigned short f2bf(float x) {
    // round-to-nearest-even bf16 truncation
    unsigned u = __float_as_uint(x);
    unsigned r = u + 0x7fffu + ((u >> 16) & 1u);
    return (unsigned short)(r >> 16);
}
__device__ __forceinline__ float bf2f(unsigned short h) {
    return __uint_as_float(((unsigned)h) << 16);
}

#define MFMA16(a, b, c) __builtin_amdgcn_mfma_f32_16x16x32_bf16((a), (b), (c), 0, 0, 0)

// ---------------------------------------------------------------------------
// Prep: split codebooks into hi/lo bf16 in MFMA B-fragment layout + cn2.
// B-frag element map (must match A build in main kernel):
//   cw = cfg*16 + (lane&15), d = ks*32 + (lane>>4)*8 + e
// cn2 uses the SAME float4-chain fp32 arithmetic as the verified fallback
// (it is reused by the exact rescore).
// ---------------------------------------------------------------------------
__global__ __launch_bounds__(NTH)
void rvq_prep(const float* __restrict__ CB, char* __restrict__ ws)
{
    const int tid = threadIdx.x;
    if (blockIdx.x < 256) {
        const int f    = blockIdx.x * NTH + tid;    // [0, 65536)
        const int lane = f & 63;
        const int ks   = (f >> 6) & 1;
        const int cfg  = (f >> 7) & 63;
        const int s    = f >> 13;
        const int cw   = cfg * 16 + (lane & 15);
        const int d0   = ks * 32 + (lane >> 4) * 8;
        const float* src = CB + ((size_t)(s * K + cw)) * CD + d0;
        const float4 x0 = *(const float4*)src;
        const float4 x1 = *(const float4*)(src + 4);
        float xs[8] = {x0.x, x0.y, x0.z, x0.w, x1.x, x1.y, x1.z, x1.w};
        s16x8 hv, lv;
        #pragma unroll
        for (int e = 0; e < 8; ++e) {
            const unsigned short hb = f2bf(xs[e]);
            hv[e] = (short)hb;
            lv[e] = (short)f2bf(xs[e] - bf2f(hb));
        }
        s16x8* dst = (s16x8*)ws + ((((size_t)(s * 64 + cfg) * 2 + ks) * 2 + 0) * 64 + lane);
        dst[0]  = hv;     // hl = 0
        dst[64] = lv;     // hl = 1
    } else {
        const int t = (blockIdx.x - 256) * NTH + tid;   // [0, 8192)
        const float4* src = (const float4*)(CB + (size_t)t * CD);
        float a = 0.f;
        #pragma unroll
        for (int c = 0; c < CD / 4; ++c) {
            const float4 v = src[c];
            a += v.x * v.x + v.y * v.y + v.z * v.z + v.w * v.w;
        }
        ((float*)(ws + CN2_OFF))[t] = a;
    }
}

// ---------------------------------------------------------------------------
// Main: per block 32 tokens x full K=1024. 4 waves; wave w owns cw [w*256, w*256+256).
// Logits via bf16x4-split MFMA (approx, well within output threshold).
// Indices via per-lane approx top-3 -> per-wave top-3 -> exact fp32 rescore of
// 12 candidates/token using the verified fallback's arithmetic expressions.
// ---------------------------------------------------------------------------
__global__ __launch_bounds__(NTH, 2)
void rvq_mfma(const float* __restrict__ Z, const float* __restrict__ CB,
              float* __restrict__ out, const char* __restrict__ ws)
{
    __shared__ float sRes[TM * LDK];     // fp32 residual, 8.7 KB
    __shared__ float sRn2[TM];
    __shared__ int   sBest[TM];
    __shared__ float sPV[TM][12];        // per-token 12 approx-best candidates
    __shared__ int   sPI[TM][12];

    const int tid  = threadIdx.x;
    const int lane = tid & 63;
    const int wid  = tid >> 6;
    const int l15  = lane & 15;
    const int lg4  = lane >> 4;
    const int gt0  = blockIdx.x * TM;
    const int b    = gt0 / T;
    const int t0   = gt0 % T;
    const int c0   = wid * 256;          // wave's codeword base

    float* __restrict__ zq  = out + ZQ_OFF;
    float* __restrict__ ido = out + IDX_OFF;
    float* __restrict__ lgo = out + LG_OFF;
    const s16x8* __restrict__ fragAll = (const s16x8*)ws;
    const float* __restrict__ cn2g    = (const float*)(ws + CN2_OFF);

    #pragma unroll 1
    for (int s = 0; s < NCB; ++s) {
        __syncthreads();   // sBest (prev stage) ready; prev readers done

        // ---- residual update (and z_q write for stage s-1) ----
        // EXACT same arithmetic as the verified fallback kernel.
        #pragma unroll
        for (int r = 0; r < (TM * CD) / (4 * NTH); ++r) {   // 2 rounds
            const int f4  = tid + r * NTH;
            const int tok = f4 >> 4;
            const int dv  = f4 & 15;
            const float4 zv = *(const float4*)(Z + (long)(gt0 + tok) * D + s * CD + dv * 4);
            float4* rp = (float4*)(&sRes[tok * LDK + dv * 4]);
            if (s == 0) {
                *rp = zv;
            } else {
                const int best = sBest[tok];
                const float4 qv = *(const float4*)(CB + (long)((s - 1) * K + best) * CD + dv * 4);
                float4 rv = *rp;
                rv.x = zv.x + (rv.x - qv.x);
                rv.y = zv.y + (rv.y - qv.y);
                rv.z = zv.z + (rv.z - qv.z);
                rv.w = zv.w + (rv.w - qv.w);
                *rp = rv;
                *(float4*)(zq + (long)(gt0 + tok) * D + (s - 1) * CD + dv * 4) = qv;
            }
        }
        __syncthreads();   // sRes ready

        // ---- residual norms (fp32, fallback-identical chain) ----
        if (tid < TM) {
            const float4* rr = (const float4*)(&sRes[tid * LDK]);
            float a = 0.f;
            #pragma unroll
            for (int c = 0; c < CD / 4; ++c) {
                const float4 v = rr[c];
                a += v.x * v.x + v.y * v.y + v.z * v.z + v.w * v.w;
            }
            sRn2[tid] = a;
        }

        // ---- build A fragments (hi/lo bf16) from sRes ----
        // A map: row = rf*16 + (lane&15), k = ks*32 + (lane>>4)*8 + e
        // (same (lg4,e)->k bijection as B, so any HW k-permutation cancels)
        s16x8 Ahi[2][2], Alo[2][2];
        #pragma unroll
        for (int rf = 0; rf < 2; ++rf) {
            #pragma unroll
            for (int ks = 0; ks < 2; ++ks) {
                const float* rp = &sRes[(rf * 16 + l15) * LDK + ks * 32 + lg4 * 8];
                const float4 x0 = *(const float4*)rp;
                const float4 x1 = *(const float4*)(rp + 4);
                float xs[8] = {x0.x, x0.y, x0.z, x0.w, x1.x, x1.y, x1.z, x1.w};
                s16x8 h, l;
                #pragma unroll
                for (int e = 0; e < 8; ++e) {
                    const unsigned short hb = f2bf(xs[e]);
                    h[e] = (short)hb;
                    l[e] = (short)f2bf(xs[e] - bf2f(hb));
                }
                Ahi[rf][ks] = h;
                Alo[rf][ks] = l;
            }
        }
        __syncthreads();   // sRn2 ready

        // ---- per-stage register setup ----
        float rn2v[2][4];
        #pragma unroll
        for (int rf = 0; rf < 2; ++rf)
            #pragma unroll
            for (int r = 0; r < 4; ++r)
                rn2v[rf][r] = sRn2[rf * 16 + lg4 * 4 + r];

        float cn2v[16];
        #pragma unroll
        for (int cf = 0; cf < 16; ++cf)
            cn2v[cf] = cn2g[s * K + c0 + cf * 16 + l15];

        float* pr0 = lgo + ((long)((b * NCB + s) * T) + t0 + lg4 * 4) * K + c0 + l15;
        float* pr1 = pr0 + (long)16 * K;

        const int kb = c0 + l15;
        // per-slot approx top-3 (sorted desc)
        float tv[2][4][3];
        int   ti[2][4][3];
        #pragma unroll
        for (int rf = 0; rf < 2; ++rf)
            #pragma unroll
            for (int r = 0; r < 4; ++r)
                #pragma unroll
                for (int p = 0; p < 3; ++p) { tv[rf][r][p] = -3.4e38f; ti[rf][r][p] = 0x7fffffff; }

        // ---- MFMA over this wave's 16 codeword-fragments, B streamed from L2 ----
        // BUGFIX (round 2 -> 3): fragment base must include the wave's codeword
        // offset (global cf = wid*16 + cf). Rounds 1-2 had all 4 waves reading
        // wave 0's fragments while labeling them with c0-based indices.
        const s16x8* fb = fragAll + (size_t)s * 16384 + (size_t)wid * 16 * 256 + lane;
        s16x8 bb[3][4];
        #pragma unroll
        for (int j = 0; j < 4; ++j) bb[0][j] = fb[0 * 256 + j * 64];
        #pragma unroll
        for (int j = 0; j < 4; ++j) bb[1][j] = fb[1 * 256 + j * 64];

        #pragma unroll
        for (int cf = 0; cf < 16; ++cf) {
            if (cf + 2 < 16) {
                #pragma unroll
                for (int j = 0; j < 4; ++j)
                    bb[(cf + 2) % 3][j] = fb[(size_t)(cf + 2) * 256 + j * 64];
            }
            const s16x8 b0 = bb[cf % 3][0];   // ks0 hi
            const s16x8 b1 = bb[cf % 3][1];   // ks0 lo
            const s16x8 b2 = bb[cf % 3][2];   // ks1 hi
            const s16x8 b3 = bb[cf % 3][3];   // ks1 lo

            f32x4 a0 = {0.f, 0.f, 0.f, 0.f};
            f32x4 a1 = {0.f, 0.f, 0.f, 0.f};
            // small-first per ks: ll, hl, lh, hh; two independent chains
            a0 = MFMA16(Alo[0][0], b1, a0);  a1 = MFMA16(Alo[1][0], b1, a1);
            a0 = MFMA16(Ahi[0][0], b1, a0);  a1 = MFMA16(Ahi[1][0], b1, a1);
            a0 = MFMA16(Alo[0][0], b0, a0);  a1 = MFMA16(Alo[1][0], b0, a1);
            a0 = MFMA16(Ahi[0][0], b0, a0);  a1 = MFMA16(Ahi[1][0], b0, a1);
            a0 = MFMA16(Alo[0][1], b3, a0);  a1 = MFMA16(Alo[1][1], b3, a1);
            a0 = MFMA16(Ahi[0][1], b3, a0);  a1 = MFMA16(Ahi[1][1], b3, a1);
            a0 = MFMA16(Alo[0][1], b2, a0);  a1 = MFMA16(Alo[1][1], b2, a1);
            a0 = MFMA16(Ahi[0][1], b2, a0);  a1 = MFMA16(Ahi[1][1], b2, a1);

            // ---- fused epilogue: logits store + per-slot top-3 track ----
            // C/D map (m89-verified): col = lane&15, row = (lane>>4)*4 + reg
            const int ki = kb + cf * 16;
            #pragma unroll
            for (int rf = 0; rf < 2; ++rf) {
                const f32x4 av = rf ? a1 : a0;
                float* prb = rf ? pr1 : pr0;
                #pragma unroll
                for (int r = 0; r < 4; ++r) {
                    const float lg = 2.0f * av[r] - (rn2v[rf][r] + cn2v[cf]);
                    __builtin_nontemporal_store(lg, prb + (long)r * K + cf * 16);
                    if (lg > tv[rf][r][2]) {
                        if (lg > tv[rf][r][1]) {
                            if (lg > tv[rf][r][0]) {
                                tv[rf][r][2] = tv[rf][r][1]; ti[rf][r][2] = ti[rf][r][1];
                                tv[rf][r][1] = tv[rf][r][0]; ti[rf][r][1] = ti[rf][r][0];
                                tv[rf][r][0] = lg;           ti[rf][r][0] = ki;
                            } else {
                                tv[rf][r][2] = tv[rf][r][1]; ti[rf][r][2] = ti[rf][r][1];
                                tv[rf][r][1] = lg;           ti[rf][r][1] = ki;
                            }
                        } else {
                            tv[rf][r][2] = lg; ti[rf][r][2] = ki;
                        }
                    }
                }
            }
        }

        // ---- per-wave top-3 per token: 3-pass pop over the 16 l15 lanes ----
        #pragma unroll
        for (int rf = 0; rf < 2; ++rf) {
            #pragma unroll
            for (int r = 0; r < 4; ++r) {
                float c0v = tv[rf][r][0], c1v = tv[rf][r][1], c2v = tv[rf][r][2];
                int   c0i = ti[rf][r][0], c1i = ti[rf][r][1], c2i = ti[rf][r][2];
                const int tok = rf * 16 + lg4 * 4 + r;
                #pragma unroll
                for (int p = 0; p < 3; ++p) {
                    float rv_ = c0v; int ri_ = c0i;
                    #pragma unroll
                    for (int off = 8; off > 0; off >>= 1) {
                        const float ov = __shfl_xor(rv_, off);
                        const int   oi = __shfl_xor(ri_, off);
                        if (ov > rv_ || (ov == rv_ && oi < ri_)) { rv_ = ov; ri_ = oi; }
                    }
                    if (l15 == 0) { sPV[tok][wid * 3 + p] = rv_; sPI[tok][wid * 3 + p] = ri_; }
                    const bool mine = (c0i == ri_);
                    c0v = mine ? c1v : c0v;  c0i = mine ? c1i : c0i;
                    c1v = mine ? c2v : c1v;  c1i = mine ? c2i : c1i;
                    c2v = mine ? -3.4e38f : c2v;
                }
            }
        }
        __syncthreads();   // sPV/sPI ready

        // ---- exact fp32 rescore of the 12 candidates per token ----
        // 8 threads per token; thread j evaluates candidates n=j and (j<4) n=j+8.
        // Arithmetic expressions are IDENTICAL to the verified fallback kernel.
        {
            const int tok = tid >> 3;
            const int j   = tid & 7;
            const float rn2 = sRn2[tok];
            const float4* rr = (const float4*)(&sRes[tok * LDK]);
            float bv = -3.4e38f; int bi = 0x7fffffff;
            #pragma unroll
            for (int pass = 0; pass < 2; ++pass) {
                const int n = j + pass * 8;
                if (n < 12) {
                    const int ci = sPI[tok][n];
                    const float4* cc = (const float4*)(CB + (long)(s * K + ci) * CD);
                    float acc = 0.f;
                    #pragma unroll
                    for (int dc = 0; dc < CD / 4; ++dc) {
                        const float4 rv = rr[dc];
                        const float4 cv = cc[dc];
                        acc += rv.x * cv.x + rv.y * cv.y + rv.z * cv.z + rv.w * cv.w;
                    }
                    const float lg = 2.0f * acc - (rn2 + cn2g[s * K + ci]);
                    if (lg > bv || (lg == bv && ci < bi)) { bv = lg; bi = ci; }
                }
            }
            #pragma unroll
            for (int off = 4; off > 0; off >>= 1) {
                const float ov = __shfl_xor(bv, off);
                const int   oi = __shfl_xor(bi, off);
                if (ov > bv || (ov == bv && oi < bi)) { bv = ov; bi = oi; }
            }
            if (j == 0) {
                sBest[tok] = bi;
                ido[(long)(b * NCB + s) * T + t0 + tok] = (float)bi;
            }
        }
    }

    // ---- final z_q chunk (stage 7 quantization) ----
    __syncthreads();
    #pragma unroll
    for (int r = 0; r < (TM * CD) / (4 * NTH); ++r) {
        const int f4  = tid + r * NTH;
        const int tok = f4 >> 4;
        const int dv  = f4 & 15;
        const int best = sBest[tok];
        const float4 qv = *(const float4*)(CB + (long)(7 * K + best) * CD + dv * 4);
        *(float4*)(zq + (long)(gt0 + tok) * D + 7 * CD + dv * 4) = qv;
    }
}

// ---------------------------------------------------------------------------
// Fallback: the previous harness-verified fp32 kernel (used if ws too small).
// ---------------------------------------------------------------------------
namespace {
constexpr int KT = 128;
}

__global__ __launch_bounds__(NTH, 2)
void rvq_kernel_fallback(const float* __restrict__ Z, const float* __restrict__ CB,
                         float* __restrict__ out)
{
    __shared__ float sCb[KT * LDK];
    __shared__ float sRes[TM * LDK];
    __shared__ float sCn2[KT];
    __shared__ float sRn2[TM];
    __shared__ int   sBest[TM];

    const int tid = threadIdx.x;
    const int kth = tid & 31;
    const int grp = tid >> 5;
    const int gt0 = blockIdx.x * TM;
    const int b   = gt0 / T;
    const int t0  = gt0 % T;

    float* __restrict__ zq  = out + ZQ_OFF;
    float* __restrict__ ido = out + IDX_OFF;
    float* __restrict__ lgo = out + LG_OFF;

    #pragma unroll 1
    for (int s = 0; s < NCB; ++s) {
        __syncthreads();
        #pragma unroll
        for (int r = 0; r < (TM * CD) / (4 * NTH); ++r) {
            const int f4  = tid + r * NTH;
            const int tok = f4 >> 4;
            const int dv  = f4 & 15;
            const float4 zv = *(const float4*)(Z + (long)(gt0 + tok) * D + s * CD + dv * 4);
            float4* rp = (float4*)(&sRes[tok * LDK + dv * 4]);
            if (s == 0) {
                *rp = zv;
            } else {
                const int best = sBest[tok];
                const float4 qv = *(const float4*)(CB + (long)((s - 1) * K + best) * CD + dv * 4);
                float4 rv = *rp;
                rv.x = zv.x + (rv.x - qv.x);
                rv.y = zv.y + (rv.y - qv.y);
                rv.z = zv.z + (rv.z - qv.z);
                rv.w = zv.w + (rv.w - qv.w);
                *rp = rv;
                *(float4*)(zq + (long)(gt0 + tok) * D + (s - 1) * CD + dv * 4) = qv;
            }
        }
        __syncthreads();

        if (tid < TM) {
            const float4* rr = (const float4*)(&sRes[tid * LDK]);
            float a = 0.f;
            #pragma unroll
            for (int c = 0; c < CD / 4; ++c) {
                const float4 v = rr[c];
                a += v.x * v.x + v.y * v.y + v.z * v.z + v.w * v.w;
            }
            sRn2[tid] = a;
        }

        float bestv[4];
        int   besti[4];
        #pragma unroll
        for (int m = 0; m < 4; ++m) { bestv[m] = -3.4e38f; besti[m] = 0; }

        #pragma unroll 1
        for (int tile = 0; tile < K / KT; ++tile) {
            __syncthreads();
            const float4* src = (const float4*)(CB + (long)(s * K + tile * KT) * CD);
            #pragma unroll
            for (int r = 0; r < (KT * CD) / (4 * NTH); ++r) {
                const int f4 = tid + r * NTH;
                const int k  = f4 >> 4;
                const int dv = f4 & 15;
                *(float4*)(&sCb[k * LDK + dv * 4]) = src[f4];
            }
            __syncthreads();

            if (tid < KT) {
                const float4* cr = (const float4*)(&sCb[tid * LDK]);
                float a = 0.f;
                #pragma unroll
                for (int c = 0; c < CD / 4; ++c) {
                    const float4 v = cr[c];
                    a += v.x * v.x + v.y * v.y + v.z * v.z + v.w * v.w;
                }
                sCn2[tid] = a;
            }
            __syncthreads();

            float acc[4][4];
            #pragma unroll
            for (int m = 0; m < 4; ++m)
                #pragma unroll
                for (int j = 0; j < 4; ++j) acc[m][j] = 0.f;

            const float4* crow[4];
            #pragma unroll
            for (int j = 0; j < 4; ++j)
                crow[j] = (const float4*)(&sCb[(j * 32 + kth) * LDK]);
            const float4* rrow[4];
            #pragma unroll
            for (int m = 0; m < 4; ++m)
                rrow[m] = (const float4*)(&sRes[(grp * 4 + m) * LDK]);

            #pragma unroll
            for (int dc = 0; dc < CD / 4; ++dc) {
                float4 rv[4];
                #pragma unroll
                for (int m = 0; m < 4; ++m) rv[m] = rrow[m][dc];
                #pragma unroll
                for (int j = 0; j < 4; ++j) {
                    const float4 cv = crow[j][dc];
                    #pragma unroll
                    for (int m = 0; m < 4; ++m) {
                        acc[m][j] += rv[m].x * cv.x + rv[m].y * cv.y
                                   + rv[m].z * cv.z + rv[m].w * cv.w;
                    }
                }
            }

            const int kbase = tile * KT;
            float* lp0 = lgo + ((long)((b * NCB + s) * T + t0 + grp * 4) * K) + kbase + kth;
            #pragma unroll
            for (int m = 0; m < 4; ++m) {
                const float rn2 = sRn2[grp * 4 + m];
                float* lp = lp0 + (long)m * K;
                #pragma unroll
                for (int j = 0; j < 4; ++j) {
                    const float cn2 = sCn2[j * 32 + kth];
                    const float lg = 2.0f * acc[m][j] - (rn2 + cn2);
                    lp[j * 32] = lg;
                    const int kidx = kbase + j * 32 + kth;
                    if (lg > bestv[m]) { bestv[m] = lg; besti[m] = kidx; }
                }
            }
        }

        #pragma unroll
        for (int m = 0; m < 4; ++m) {
            float v  = bestv[m];
            int   ii = besti[m];
            #pragma unroll
            for (int off = 16; off > 0; off >>= 1) {
                const float ov = __shfl_xor(v, off);
                const int   oi = __shfl_xor(ii, off);
                if (ov > v || (ov == v && oi < ii)) { v = ov; ii = oi; }
            }
            if (kth == 0) {
                sBest[grp * 4 + m] = ii;
                ido[(long)(b * NCB + s) * T + t0 + grp * 4 + m] = (float)ii;
            }
        }
    }

    __syncthreads();
    #pragma unroll
    for (int r = 0; r < (TM * CD) / (4 * NTH); ++r) {
        const int f4  = tid + r * NTH;
        const int tok = f4 >> 4;
        const int dv  = f4 & 15;
        const int best = sBest[tok];
        const float4 qv = *(const float4*)(CB + (long)(7 * K + best) * CD + dv * 4);
        *(float4*)(zq + (long)(gt0 + tok) * D + 7 * CD + dv * 4) = qv;
    }
}

extern "C" void kernel_launch(void* const* d_in, const int* in_sizes, int n_in,
                              void* d_out, int out_size, void* d_ws, size_t ws_size,
                              hipStream_t stream)
{
    const float* Z   = (const float*)d_in[0];
    const float* CBp = (const float*)d_in[1];
    float* out = (float*)d_out;

    if (d_ws != nullptr && ws_size >= WS_NEEDED) {
        hipLaunchKernelGGL(rvq_prep, dim3(288), dim3(NTH), 0, stream, CBp, (char*)d_ws);
        hipLaunchKernelGGL(rvq_mfma, dim3((B * T) / TM), dim3(NTH), 0, stream,
                           Z, CBp, out, (const char*)d_ws);
    } else {
        hipLaunchKernelGGL(rvq_kernel_fallback, dim3((B * T) / TM), dim3(NTH), 0, stream,
                           Z, CBp, out);
    }
}